// Round 1
// baseline (946.593 us; speedup 1.0000x reference)
//
#include <hip/hip_runtime.h>

#define NN 100000
#define EE 3200000
#define SLOPE 0.2f

constexpr int EP = EE + NN;                 // edges incl. one self-loop per node
constexpr int NB = (NN + 1023) / 1024;      // scan blocks (98)

// ---------------- CSR build ----------------

__global__ void k_deg(const int* __restrict__ dst, int* __restrict__ deg) {
    int e = blockIdx.x * 256 + threadIdx.x;
    if (e < EE) atomicAdd(&deg[dst[e]], 1);
}

// per-block exclusive scan of (deg[n]+1), block totals to bsums
__global__ void k_scan1(const int* __restrict__ deg, int* __restrict__ offs,
                        int* __restrict__ bsums) {
    __shared__ int sd[256];
    int t = threadIdx.x;
    int base = blockIdx.x * 1024 + t * 4;
    int v[4];
#pragma unroll
    for (int i = 0; i < 4; i++) v[i] = (base + i < NN) ? deg[base + i] + 1 : 0;
    int tsum = v[0] + v[1] + v[2] + v[3];
    sd[t] = tsum;
    __syncthreads();
    for (int off = 1; off < 256; off <<= 1) {
        int val = (t >= off) ? sd[t - off] : 0;
        __syncthreads();
        sd[t] += val;
        __syncthreads();
    }
    int excl = sd[t] - tsum;
    if (t == 255) bsums[blockIdx.x] = sd[255];
    int run = excl;
#pragma unroll
    for (int i = 0; i < 4; i++) {
        if (base + i < NN) offs[base + i] = run;
        run += v[i];
    }
}

__global__ void k_scan2(int* bsums) {
    __shared__ int sd[128];
    int t = threadIdx.x;
    int v = (t < NB) ? bsums[t] : 0;
    sd[t] = v;
    __syncthreads();
    for (int off = 1; off < 128; off <<= 1) {
        int val = (t >= off) ? sd[t - off] : 0;
        __syncthreads();
        sd[t] += val;
        __syncthreads();
    }
    if (t < NB) bsums[t] = sd[t] - v;   // exclusive
}

__global__ void k_scan3(int* __restrict__ offs, const int* __restrict__ bsums,
                        int* __restrict__ cursor) {
    int n = blockIdx.x * 256 + threadIdx.x;
    if (n < NN) {
        int fin = offs[n] + bsums[n >> 10];
        offs[n] = fin;
        cursor[n] = fin;
    }
    if (n == 0) offs[NN] = EP;
}

__global__ void k_scatter(const int* __restrict__ src, const int* __restrict__ dst,
                          const float* __restrict__ ea, int* __restrict__ cursor,
                          int* __restrict__ csr_src, float* __restrict__ csr_ea) {
    int e = blockIdx.x * 256 + threadIdx.x;
    if (e < EE) {
        int d = dst[e];
        int pos = atomicAdd(&cursor[d], 1);
        csr_src[pos] = src[e];
        csr_ea[pos] = ea[e];
    }
}

// self-loop edge_attr = mean of incoming edge attrs; append loop edge per node
__global__ void k_loop(const int* __restrict__ offs, const int* __restrict__ deg,
                       int* __restrict__ csr_src, float* __restrict__ csr_ea) {
    int node = blockIdx.x * (blockDim.x >> 6) + (threadIdx.x >> 6);
    if (node >= NN) return;
    int lane = threadIdx.x & 63;
    int base = offs[node];
    int dn = deg[node];
    float s = 0.f;
    for (int i = lane; i < dn; i += 64) s += csr_ea[base + i];
#pragma unroll
    for (int off = 32; off >= 1; off >>= 1) s += __shfl_xor(s, off);
    if (lane == 0) {
        csr_src[base + dn] = node;
        csr_ea[base + dn] = s / fmaxf((float)dn, 1.0f);
    }
}

// c = sum_j We[0][j] * a_e[j]  (edge-attr path collapses to a per-edge scalar)
__global__ void k_const(const float* __restrict__ We1, const float* __restrict__ ae1,
                        const float* __restrict__ We2, const float* __restrict__ ae2,
                        float* __restrict__ cbuf) {
    int lane = threadIdx.x & 63;
    int comp = lane & 31;
    float p = (lane < 32) ? We1[comp] * ae1[comp] : We2[comp] * ae2[comp];
#pragma unroll
    for (int off = 16; off >= 1; off >>= 1) p += __shfl_xor(p, off);
    if (comp == 0) cbuf[lane >> 5] = p;
}

// ---------------- dense node transforms ----------------

// layer 1: x = concat(emb[id], feat) [17]; h = x@W1 [32]; as = h.a_s; ad = h.a_d
__global__ void k_h1(const int* __restrict__ ids, const float* __restrict__ feat,
                     const float* __restrict__ emb, const float* __restrict__ W,
                     const float* __restrict__ avs, const float* __restrict__ avd,
                     float* __restrict__ h, float* __restrict__ as_, float* __restrict__ ad_) {
    int n = blockIdx.x * 256 + threadIdx.x;
    if (n >= NN) return;
    float hv[32];
#pragma unroll
    for (int j = 0; j < 32; j++) hv[j] = 0.f;
    int id = ids[n];
    const float4* e4 = (const float4*)(emb + (size_t)id * 16);
#pragma unroll
    for (int k4 = 0; k4 < 4; k4++) {
        float4 xv = e4[k4];
        const float* wr = W + k4 * 4 * 32;
#pragma unroll
        for (int j = 0; j < 32; j++)
            hv[j] += xv.x * wr[j] + xv.y * wr[32 + j] + xv.z * wr[64 + j] + xv.w * wr[96 + j];
    }
    float f = feat[n];
#pragma unroll
    for (int j = 0; j < 32; j++) hv[j] += f * W[16 * 32 + j];
    float s = 0.f, d = 0.f;
#pragma unroll
    for (int j = 0; j < 32; j++) { s += hv[j] * avs[j]; d += hv[j] * avd[j]; }
    as_[n] = s;
    ad_[n] = d;
    float4* h4 = (float4*)(h + (size_t)n * 32);
#pragma unroll
    for (int q = 0; q < 8; q++)
        h4[q] = make_float4(hv[4 * q], hv[4 * q + 1], hv[4 * q + 2], hv[4 * q + 3]);
}

// layer 2: h = x2@W2 [32]; as/ad dots
__global__ void k_h2(const float* __restrict__ x, const float* __restrict__ W,
                     const float* __restrict__ avs, const float* __restrict__ avd,
                     float* __restrict__ h, float* __restrict__ as_, float* __restrict__ ad_) {
    int n = blockIdx.x * 256 + threadIdx.x;
    if (n >= NN) return;
    float hv[32];
#pragma unroll
    for (int j = 0; j < 32; j++) hv[j] = 0.f;
    const float4* x4 = (const float4*)(x + (size_t)n * 32);
#pragma unroll
    for (int k4 = 0; k4 < 8; k4++) {
        float4 xv = x4[k4];
        const float* wr = W + k4 * 4 * 32;
#pragma unroll
        for (int j = 0; j < 32; j++)
            hv[j] += xv.x * wr[j] + xv.y * wr[32 + j] + xv.z * wr[64 + j] + xv.w * wr[96 + j];
    }
    float s = 0.f, d = 0.f;
#pragma unroll
    for (int j = 0; j < 32; j++) { s += hv[j] * avs[j]; d += hv[j] * avd[j]; }
    as_[n] = s;
    ad_[n] = d;
    float4* h4 = (float4*)(h + (size_t)n * 32);
#pragma unroll
    for (int q = 0; q < 8; q++)
        h4[q] = make_float4(hv[4 * q], hv[4 * q + 1], hv[4 * q + 2], hv[4 * q + 3]);
}

// ---------------- GAT aggregation: one wave per dst node ----------------
// lanes = (slot 0..1) x (comp 0..31). Softmax computed without max-subtraction
// (alphas are O(1) for these inits; exp stays far inside fp32 range).
template <bool FINAL>
__global__ void k_gat(const int* __restrict__ offs, const int* __restrict__ csr_src,
                      const float* __restrict__ csr_ea, const float* __restrict__ h,
                      const float* __restrict__ as_, const float* __restrict__ ad_,
                      const float* __restrict__ cbuf, int cidx,
                      const float* __restrict__ bias,
                      const float* __restrict__ lw, const float* __restrict__ lb,
                      float* __restrict__ out) {
    int node = blockIdx.x * (blockDim.x >> 6) + (threadIdx.x >> 6);
    if (node >= NN) return;
    int lane = threadIdx.x & 63;
    int comp = lane & 31;
    int slot = lane >> 5;
    int base = offs[node];
    int cnt = offs[node + 1] - base;       // >= 1 (self-loop)
    float c = cbuf[cidx];
    float adn = ad_[node];
    float acc = 0.f, exsum = 0.f;
    for (int i = 0; i < cnt; i += 2) {
        int idx = i + slot;
        bool valid = idx < cnt;
        int pos = base + (valid ? idx : 0);
        int s = csr_src[pos];
        float ea = csr_ea[pos];
        float a = as_[s] + adn + c * ea;
        a = (a >= 0.f) ? a : SLOPE * a;
        float ex = valid ? __expf(a) : 0.f;
        acc += ex * h[(size_t)s * 32 + comp];
        if (comp == 0) exsum += ex;
    }
    acc += __shfl_xor(acc, 32);            // combine the two edge slots
    exsum += __shfl_xor(exsum, 32);
    float denom = __shfl(exsum, 0) + 1e-16f;
    float o = acc / denom + bias[comp];
    if (!FINAL) {
        o = fmaxf(o, 0.f);                 // relu between layers
        if (lane < 32) out[(size_t)node * 32 + comp] = o;
    } else {
        float y = o * lw[comp];            // fused final linear 32 -> 1
#pragma unroll
        for (int off = 16; off >= 1; off >>= 1) y += __shfl_xor(y, off);
        if (lane == 0) out[node] = y + lb[0];
    }
}

// ---------------- launch ----------------

extern "C" void kernel_launch(void* const* d_in, const int* in_sizes, int n_in,
                              void* d_out, int out_size, void* d_ws, size_t ws_size,
                              hipStream_t stream) {
    const int* x_ids = (const int*)d_in[0];
    const float* x_feat = (const float*)d_in[1];
    const int* src = (const int*)d_in[2];
    const int* dst = (const int*)d_in[3];
    const float* eattr = (const float*)d_in[4];
    const float* emb = (const float*)d_in[5];
    const float* W1 = (const float*)d_in[6];
    const float* a_s1 = (const float*)d_in[7];
    const float* a_d1 = (const float*)d_in[8];
    const float* We1 = (const float*)d_in[9];
    const float* a_e1 = (const float*)d_in[10];
    const float* b1 = (const float*)d_in[11];
    const float* W2 = (const float*)d_in[12];
    const float* a_s2 = (const float*)d_in[13];
    const float* a_d2 = (const float*)d_in[14];
    const float* We2 = (const float*)d_in[15];
    const float* a_e2 = (const float*)d_in[16];
    const float* b2 = (const float*)d_in[17];
    const float* lin_w = (const float*)d_in[18];
    const float* lin_b = (const float*)d_in[19];

    // workspace bump allocator (256B aligned slices), total ~54 MB
    char* p = (char*)d_ws;
    auto alloc = [&](size_t bytes) {
        void* r = (void*)p;
        p += (bytes + 255) & ~(size_t)255;
        return r;
    };
    int* deg = (int*)alloc(NN * 4);
    int* offs = (int*)alloc((NN + 1) * 4);
    int* cursor = (int*)alloc(NN * 4);
    int* bsums = (int*)alloc(NB * 4);
    float* cbuf = (float*)alloc(2 * 4);
    int* csr_src = (int*)alloc((size_t)EP * 4);
    float* csr_ea = (float*)alloc((size_t)EP * 4);
    float* hbuf = (float*)alloc((size_t)NN * 32 * 4);
    float* asb = (float*)alloc(NN * 4);
    float* adb = (float*)alloc(NN * 4);
    float* x2 = (float*)alloc((size_t)NN * 32 * 4);
    (void)ws_size; (void)in_sizes; (void)n_in; (void)out_size;

    hipMemsetAsync(deg, 0, NN * 4, stream);

    const int EB = (EE + 255) / 256;
    const int NBT = (NN + 255) / 256;
    const int NW = (NN + 3) / 4;   // wave-per-node kernels, 4 waves/block

    k_deg<<<EB, 256, 0, stream>>>(dst, deg);
    k_scan1<<<NB, 256, 0, stream>>>(deg, offs, bsums);
    k_scan2<<<1, 128, 0, stream>>>(bsums);
    k_scan3<<<NBT, 256, 0, stream>>>(offs, bsums, cursor);
    k_scatter<<<EB, 256, 0, stream>>>(src, dst, eattr, cursor, csr_src, csr_ea);
    k_loop<<<NW, 256, 0, stream>>>(offs, deg, csr_src, csr_ea);
    k_const<<<1, 64, 0, stream>>>(We1, a_e1, We2, a_e2, cbuf);

    k_h1<<<NBT, 256, 0, stream>>>(x_ids, x_feat, emb, W1, a_s1, a_d1, hbuf, asb, adb);
    k_gat<false><<<NW, 256, 0, stream>>>(offs, csr_src, csr_ea, hbuf, asb, adb,
                                         cbuf, 0, b1, nullptr, nullptr, x2);
    k_h2<<<NBT, 256, 0, stream>>>(x2, W2, a_s2, a_d2, hbuf, asb, adb);
    k_gat<true><<<NW, 256, 0, stream>>>(offs, csr_src, csr_ea, hbuf, asb, adb,
                                        cbuf, 1, b2, lin_w, lin_b, (float*)d_out);
}

// Round 2
// 431.040 us; speedup vs baseline: 2.1961x; 2.1961x over previous
//
#include <hip/hip_runtime.h>

#define NN 100000
#define EE 3200000
#define SLOPE 0.2f

constexpr int EP  = EE + NN;          // edges incl. one self-loop per node
constexpr int NBK = (NN + 255) / 256; // 391 dst-buckets of 256 nodes

// ---------------- CSR build (bucketed, low write-amplification) ----------------

// 391-bucket histogram of dst>>8
__global__ void k_hist(const int* __restrict__ dst, int* __restrict__ cnt) {
    __shared__ int h[NBK];
    int t = threadIdx.x;
    for (int i = t; i < NBK; i += 256) h[i] = 0;
    __syncthreads();
    int base = blockIdx.x * 4096;
#pragma unroll
    for (int j = 0; j < 16; j++) {
        int e = base + j * 256 + t;
        if (e < EE) atomicAdd(&h[dst[e] >> 8], 1);
    }
    __syncthreads();
    for (int i = t; i < NBK; i += 256)
        if (h[i]) atomicAdd(&cnt[i], h[i]);
}

// scan bucket counts -> staging bases (edges only) and final bases (edges + self-loop slots)
__global__ void k_scanb(const int* __restrict__ cnt, int* __restrict__ sbase,
                        int* __restrict__ fbase, int* __restrict__ curA) {
    __shared__ int a1[512], a2[512];
    int t = threadIdx.x;
    int v1 = (t < NBK) ? cnt[t] : 0;
    int npb = (t < NBK) ? min(256, NN - (t << 8)) : 0;
    int v2 = v1 + npb;
    a1[t] = v1; a2[t] = v2;
    __syncthreads();
    for (int off = 1; off < 512; off <<= 1) {
        int x1 = (t >= off) ? a1[t - off] : 0;
        int x2 = (t >= off) ? a2[t - off] : 0;
        __syncthreads();
        a1[t] += x1; a2[t] += x2;
        __syncthreads();
    }
    if (t < NBK) {
        sbase[t] = a1[t] - v1;
        fbase[t] = a2[t] - v2;
        curA[t]  = a1[t] - v1;
    }
}

// scatter edges into bucket-contiguous staging; per-block chunk reservation keeps
// writes clustered (low HBM write amplification). record = {src | dstlow<<17, ea}
__global__ void k_bucket(const int* __restrict__ src, const int* __restrict__ dst,
                         const float* __restrict__ ea, int* __restrict__ curA,
                         int2* __restrict__ stage) {
    __shared__ int h[NBK];
    __shared__ int cur[NBK];
    int t = threadIdx.x;
    for (int i = t; i < NBK; i += 256) h[i] = 0;
    __syncthreads();
    int base = blockIdx.x * 8192;
#pragma unroll
    for (int j = 0; j < 32; j++) {
        int e = base + j * 256 + t;
        if (e < EE) atomicAdd(&h[dst[e] >> 8], 1);
    }
    __syncthreads();
    for (int i = t; i < NBK; i += 256)
        cur[i] = h[i] ? atomicAdd(&curA[i], h[i]) : 0;
    __syncthreads();
#pragma unroll
    for (int j = 0; j < 32; j++) {
        int e = base + j * 256 + t;
        if (e < EE) {
            int d = dst[e];
            int pos = atomicAdd(&cur[d >> 8], 1);
            stage[pos] = make_int2(src[e] | ((d & 255) << 17), __float_as_int(ea[e]));
        }
    }
}

// one block per bucket: local per-node offsets + self-loop mean + final CSR.
// bucket window (~64KB) is L2-resident -> node-level scatter has no HBM amp.
__global__ void k_build(const int* __restrict__ cnt, const int* __restrict__ sbase,
                        const int* __restrict__ fbase, const int2* __restrict__ stage,
                        int2* __restrict__ csr, int* __restrict__ offs) {
    __shared__ int ldeg[256];
    __shared__ float esum[256];
    __shared__ int sc[256];
    __shared__ int lcur[256];
    int b = blockIdx.x, t = threadIdx.x;
    int nbase = b << 8;
    int npb = min(256, NN - nbase);
    int c = cnt[b];
    const int2* ep = stage + sbase[b];
    int fb = fbase[b];
    ldeg[t] = 0; esum[t] = 0.f;
    __syncthreads();
    for (int i = t; i < c; i += 256) {
        int2 e = ep[i];
        int n = (e.x >> 17) & 255;
        atomicAdd(&ldeg[n], 1);
        atomicAdd(&esum[n], __int_as_float(e.y));
    }
    __syncthreads();
    int slots = (t < npb) ? ldeg[t] + 1 : 0;   // +1 self-loop slot
    sc[t] = slots;
    __syncthreads();
    for (int off = 1; off < 256; off <<= 1) {
        int x = (t >= off) ? sc[t - off] : 0;
        __syncthreads();
        sc[t] += x;
        __syncthreads();
    }
    int myoff = fb + sc[t] - slots;
    if (t < npb) { offs[nbase + t] = myoff; lcur[t] = myoff; }
    __syncthreads();
    for (int i = t; i < c; i += 256) {
        int2 e = ep[i];
        int n = (e.x >> 17) & 255;
        int pos = atomicAdd(&lcur[n], 1);
        csr[pos] = e;
    }
    __syncthreads();
    if (t < npb) {
        int pos = lcur[t];                      // == segment end (self-loop slot)
        float mean = esum[t] / fmaxf((float)ldeg[t], 1.0f);
        csr[pos] = make_int2(nbase + t, __float_as_int(mean));
    }
    if (b == 0 && t == 0) offs[NN] = EP;
}

// c = sum_j We[0][j] * a_e[j]
__global__ void k_const(const float* __restrict__ We1, const float* __restrict__ ae1,
                        const float* __restrict__ We2, const float* __restrict__ ae2,
                        float* __restrict__ cbuf) {
    int lane = threadIdx.x & 63;
    int comp = lane & 31;
    float p = (lane < 32) ? We1[comp] * ae1[comp] : We2[comp] * ae2[comp];
#pragma unroll
    for (int off = 16; off >= 1; off >>= 1) p += __shfl_xor(p, off);
    if (comp == 0) cbuf[lane >> 5] = p;
}

// ---------------- dense node transforms ----------------

__global__ void k_h1(const int* __restrict__ ids, const float* __restrict__ feat,
                     const float* __restrict__ emb, const float* __restrict__ W,
                     const float* __restrict__ avs, const float* __restrict__ avd,
                     float* __restrict__ h, float* __restrict__ as_, float* __restrict__ ad_) {
    int n = blockIdx.x * 256 + threadIdx.x;
    if (n >= NN) return;
    float hv[32];
#pragma unroll
    for (int j = 0; j < 32; j++) hv[j] = 0.f;
    int id = ids[n];
    const float4* e4 = (const float4*)(emb + (size_t)id * 16);
#pragma unroll
    for (int k4 = 0; k4 < 4; k4++) {
        float4 xv = e4[k4];
        const float* wr = W + k4 * 4 * 32;
#pragma unroll
        for (int j = 0; j < 32; j++)
            hv[j] += xv.x * wr[j] + xv.y * wr[32 + j] + xv.z * wr[64 + j] + xv.w * wr[96 + j];
    }
    float f = feat[n];
#pragma unroll
    for (int j = 0; j < 32; j++) hv[j] += f * W[16 * 32 + j];
    float s = 0.f, d = 0.f;
#pragma unroll
    for (int j = 0; j < 32; j++) { s += hv[j] * avs[j]; d += hv[j] * avd[j]; }
    as_[n] = s;
    ad_[n] = d;
    float4* h4 = (float4*)(h + (size_t)n * 32);
#pragma unroll
    for (int q = 0; q < 8; q++)
        h4[q] = make_float4(hv[4 * q], hv[4 * q + 1], hv[4 * q + 2], hv[4 * q + 3]);
}

__global__ void k_h2(const float* __restrict__ x, const float* __restrict__ W,
                     const float* __restrict__ avs, const float* __restrict__ avd,
                     float* __restrict__ h, float* __restrict__ as_, float* __restrict__ ad_) {
    int n = blockIdx.x * 256 + threadIdx.x;
    if (n >= NN) return;
    float hv[32];
#pragma unroll
    for (int j = 0; j < 32; j++) hv[j] = 0.f;
    const float4* x4 = (const float4*)(x + (size_t)n * 32);
#pragma unroll
    for (int k4 = 0; k4 < 8; k4++) {
        float4 xv = x4[k4];
        const float* wr = W + k4 * 4 * 32;
#pragma unroll
        for (int j = 0; j < 32; j++)
            hv[j] += xv.x * wr[j] + xv.y * wr[32 + j] + xv.z * wr[64 + j] + xv.w * wr[96 + j];
    }
    float s = 0.f, d = 0.f;
#pragma unroll
    for (int j = 0; j < 32; j++) { s += hv[j] * avs[j]; d += hv[j] * avd[j]; }
    as_[n] = s;
    ad_[n] = d;
    float4* h4 = (float4*)(h + (size_t)n * 32);
#pragma unroll
    for (int q = 0; q < 8; q++)
        h4[q] = make_float4(hv[4 * q], hv[4 * q + 1], hv[4 * q + 2], hv[4 * q + 3]);
}

// ---------------- GAT aggregation: one wave per dst node, 8 edges/iter ----------------
template <bool FINAL>
__global__ void k_gat(const int* __restrict__ offs, const int2* __restrict__ csr,
                      const float* __restrict__ h, const float* __restrict__ as_,
                      const float* __restrict__ ad_, const float* __restrict__ cbuf,
                      int cidx, const float* __restrict__ bias,
                      const float* __restrict__ lw, const float* __restrict__ lb,
                      float* __restrict__ out) {
    int node = blockIdx.x * 4 + (threadIdx.x >> 6);
    if (node >= NN) return;
    int lane = threadIdx.x & 63;
    int comp = lane & 31;
    int slot = lane >> 5;
    int base = offs[node];
    int cnt = offs[node + 1] - base;       // >= 1 (self-loop)
    float c = cbuf[cidx];
    float adn = ad_[node];
    float acc = 0.f, exs = 0.f;
    for (int i = 0; i < cnt; i += 8) {
        int2 e[4]; bool val[4];
#pragma unroll
        for (int j = 0; j < 4; j++) {
            int idx = i + slot + 2 * j;
            val[j] = idx < cnt;
            e[j] = csr[base + (val[j] ? idx : 0)];
        }
        float asv[4], hv[4];
#pragma unroll
        for (int j = 0; j < 4; j++) {
            int s = e[j].x & 0x1FFFF;
            asv[j] = as_[s];
            hv[j] = h[(size_t)s * 32 + comp];
        }
#pragma unroll
        for (int j = 0; j < 4; j++) {
            float a = asv[j] + adn + c * __int_as_float(e[j].y);
            a = (a >= 0.f) ? a : SLOPE * a;
            float ex = val[j] ? __expf(a) : 0.f;
            acc += ex * hv[j];
            exs += ex;
        }
    }
    acc += __shfl_xor(acc, 32);            // combine the two edge slots
    exs += __shfl_xor(exs, 32);
    float o = acc / (exs + 1e-16f) + bias[comp];
    if (!FINAL) {
        o = fmaxf(o, 0.f);
        if (lane < 32) out[(size_t)node * 32 + comp] = o;
    } else {
        float y = o * lw[comp];            // fused final linear 32 -> 1
#pragma unroll
        for (int off = 16; off >= 1; off >>= 1) y += __shfl_xor(y, off);
        if (lane == 0) out[node] = y + lb[0];
    }
}

// ---------------- launch ----------------

extern "C" void kernel_launch(void* const* d_in, const int* in_sizes, int n_in,
                              void* d_out, int out_size, void* d_ws, size_t ws_size,
                              hipStream_t stream) {
    const int* x_ids = (const int*)d_in[0];
    const float* x_feat = (const float*)d_in[1];
    const int* src = (const int*)d_in[2];
    const int* dst = (const int*)d_in[3];
    const float* eattr = (const float*)d_in[4];
    const float* emb = (const float*)d_in[5];
    const float* W1 = (const float*)d_in[6];
    const float* a_s1 = (const float*)d_in[7];
    const float* a_d1 = (const float*)d_in[8];
    const float* We1 = (const float*)d_in[9];
    const float* a_e1 = (const float*)d_in[10];
    const float* b1 = (const float*)d_in[11];
    const float* W2 = (const float*)d_in[12];
    const float* a_s2 = (const float*)d_in[13];
    const float* a_d2 = (const float*)d_in[14];
    const float* We2 = (const float*)d_in[15];
    const float* a_e2 = (const float*)d_in[16];
    const float* b2 = (const float*)d_in[17];
    const float* lin_w = (const float*)d_in[18];
    const float* lin_b = (const float*)d_in[19];

    char* p = (char*)d_ws;
    auto alloc = [&](size_t bytes) {
        void* r = (void*)p;
        p += (bytes + 255) & ~(size_t)255;
        return r;
    };
    int* cnt = (int*)alloc(NBK * 4);
    int* sbase = (int*)alloc(NBK * 4);
    int* fbase = (int*)alloc(NBK * 4);
    int* curA = (int*)alloc(NBK * 4);
    float* cbuf = (float*)alloc(2 * 4);
    int* offs = (int*)alloc((NN + 1) * 4);
    float* asb = (float*)alloc(NN * 4);
    float* adb = (float*)alloc(NN * 4);
    int2* csr = (int2*)alloc((size_t)EP * 8);
    // stage (EE*8 = 25.6MB) is dead after k_build; alias it with hbuf+x2 (2*12.8MB)
    void* regionA = alloc((size_t)EE * 8);
    int2* stage = (int2*)regionA;
    float* hbuf = (float*)regionA;
    float* x2 = hbuf + (size_t)NN * 32;
    (void)ws_size; (void)in_sizes; (void)n_in; (void)out_size;

    hipMemsetAsync(cnt, 0, NBK * 4, stream);

    const int HB = (EE + 4095) / 4096;      // 782
    const int BB = (EE + 8191) / 8192;      // 391
    const int NBT = (NN + 255) / 256;       // 391
    const int NW = (NN + 3) / 4;            // 25000, 4 waves/block

    k_hist<<<HB, 256, 0, stream>>>(dst, cnt);
    k_scanb<<<1, 512, 0, stream>>>(cnt, sbase, fbase, curA);
    k_bucket<<<BB, 256, 0, stream>>>(src, dst, eattr, curA, stage);
    k_build<<<NBK, 256, 0, stream>>>(cnt, sbase, fbase, stage, csr, offs);
    k_const<<<1, 64, 0, stream>>>(We1, a_e1, We2, a_e2, cbuf);

    k_h1<<<NBT, 256, 0, stream>>>(x_ids, x_feat, emb, W1, a_s1, a_d1, hbuf, asb, adb);
    k_gat<false><<<NW, 256, 0, stream>>>(offs, csr, hbuf, asb, adb, cbuf, 0, b1,
                                         nullptr, nullptr, x2);
    k_h2<<<NBT, 256, 0, stream>>>(x2, W2, a_s2, a_d2, hbuf, asb, adb);
    k_gat<true><<<NW, 256, 0, stream>>>(offs, csr, hbuf, asb, adb, cbuf, 1, b2,
                                        lin_w, lin_b, (float*)d_out);
}

// Round 3
// 422.898 us; speedup vs baseline: 2.2383x; 1.0193x over previous
//
#include <hip/hip_runtime.h>

#define NN 100000
#define EE 3200000
#define SLOPE 0.2f

constexpr int EP  = EE + NN;          // edges incl. one self-loop per node
constexpr int NBK = (NN + 255) / 256; // 391 dst-buckets of 256 nodes

// ---------------- CSR build (bucketed, low write-amplification) ----------------

// 391-bucket histogram of dst>>8
__global__ void k_hist(const int* __restrict__ dst, int* __restrict__ cnt) {
    __shared__ int h[NBK];
    int t = threadIdx.x;
    for (int i = t; i < NBK; i += 256) h[i] = 0;
    __syncthreads();
    int base = blockIdx.x * 4096;
#pragma unroll
    for (int j = 0; j < 16; j++) {
        int e = base + j * 256 + t;
        if (e < EE) atomicAdd(&h[dst[e] >> 8], 1);
    }
    __syncthreads();
    for (int i = t; i < NBK; i += 256)
        if (h[i]) atomicAdd(&cnt[i], h[i]);
}

// scan bucket counts -> staging bases (edges only) and final bases (edges + self-loop slots)
__global__ void k_scanb(const int* __restrict__ cnt, int* __restrict__ sbase,
                        int* __restrict__ fbase, int* __restrict__ curA) {
    __shared__ int a1[512], a2[512];
    int t = threadIdx.x;
    int v1 = (t < NBK) ? cnt[t] : 0;
    int npb = (t < NBK) ? min(256, NN - (t << 8)) : 0;
    int v2 = v1 + npb;
    a1[t] = v1; a2[t] = v2;
    __syncthreads();
    for (int off = 1; off < 512; off <<= 1) {
        int x1 = (t >= off) ? a1[t - off] : 0;
        int x2 = (t >= off) ? a2[t - off] : 0;
        __syncthreads();
        a1[t] += x1; a2[t] += x2;
        __syncthreads();
    }
    if (t < NBK) {
        sbase[t] = a1[t] - v1;
        fbase[t] = a2[t] - v2;
        curA[t]  = a1[t] - v1;
    }
}

// scatter edges into bucket-contiguous staging; per-block chunk reservation keeps
// writes clustered. record = {src | dstlow<<17, ea}
__global__ void k_bucket(const int* __restrict__ src, const int* __restrict__ dst,
                         const float* __restrict__ ea, int* __restrict__ curA,
                         int2* __restrict__ stage) {
    __shared__ int h[NBK];
    __shared__ int cur[NBK];
    int t = threadIdx.x;
    for (int i = t; i < NBK; i += 256) h[i] = 0;
    __syncthreads();
    int base = blockIdx.x * 8192;
#pragma unroll
    for (int j = 0; j < 32; j++) {
        int e = base + j * 256 + t;
        if (e < EE) atomicAdd(&h[dst[e] >> 8], 1);
    }
    __syncthreads();
    for (int i = t; i < NBK; i += 256)
        cur[i] = h[i] ? atomicAdd(&curA[i], h[i]) : 0;
    __syncthreads();
#pragma unroll
    for (int j = 0; j < 32; j++) {
        int e = base + j * 256 + t;
        if (e < EE) {
            int d = dst[e];
            int pos = atomicAdd(&cur[d >> 8], 1);
            stage[pos] = make_int2(src[e] | ((d & 255) << 17), __float_as_int(ea[e]));
        }
    }
}

// one block per bucket: local per-node offsets + self-loop mean + final CSR.
__global__ void k_build(const int* __restrict__ cnt, const int* __restrict__ sbase,
                        const int* __restrict__ fbase, const int2* __restrict__ stage,
                        int2* __restrict__ csr, int* __restrict__ offs) {
    __shared__ int ldeg[256];
    __shared__ float esum[256];
    __shared__ int sc[256];
    __shared__ int lcur[256];
    int b = blockIdx.x, t = threadIdx.x;
    int nbase = b << 8;
    int npb = min(256, NN - nbase);
    int c = cnt[b];
    const int2* ep = stage + sbase[b];
    int fb = fbase[b];
    ldeg[t] = 0; esum[t] = 0.f;
    __syncthreads();
    for (int i = t; i < c; i += 256) {
        int2 e = ep[i];
        int n = (e.x >> 17) & 255;
        atomicAdd(&ldeg[n], 1);
        atomicAdd(&esum[n], __int_as_float(e.y));
    }
    __syncthreads();
    int slots = (t < npb) ? ldeg[t] + 1 : 0;   // +1 self-loop slot
    sc[t] = slots;
    __syncthreads();
    for (int off = 1; off < 256; off <<= 1) {
        int x = (t >= off) ? sc[t - off] : 0;
        __syncthreads();
        sc[t] += x;
        __syncthreads();
    }
    int myoff = fb + sc[t] - slots;
    if (t < npb) { offs[nbase + t] = myoff; lcur[t] = myoff; }
    __syncthreads();
    for (int i = t; i < c; i += 256) {
        int2 e = ep[i];
        int n = (e.x >> 17) & 255;
        int pos = atomicAdd(&lcur[n], 1);
        csr[pos] = e;
    }
    __syncthreads();
    if (t < npb) {
        int pos = lcur[t];                      // == segment end (self-loop slot)
        float mean = esum[t] / fmaxf((float)ldeg[t], 1.0f);
        csr[pos] = make_int2(nbase + t, __float_as_int(mean));
    }
    if (b == 0 && t == 0) offs[NN] = EP;
}

// c = sum_j We[0][j] * a_e[j]
__global__ void k_const(const float* __restrict__ We1, const float* __restrict__ ae1,
                        const float* __restrict__ We2, const float* __restrict__ ae2,
                        float* __restrict__ cbuf) {
    int lane = threadIdx.x & 63;
    int comp = lane & 31;
    float p = (lane < 32) ? We1[comp] * ae1[comp] : We2[comp] * ae2[comp];
#pragma unroll
    for (int off = 16; off >= 1; off >>= 1) p += __shfl_xor(p, off);
    if (comp == 0) cbuf[lane >> 5] = p;
}

// ---------------- dense node transforms ----------------

__global__ void k_h1(const int* __restrict__ ids, const float* __restrict__ feat,
                     const float* __restrict__ emb, const float* __restrict__ W,
                     const float* __restrict__ avs, const float* __restrict__ avd,
                     float* __restrict__ h, float* __restrict__ as_, float* __restrict__ ad_) {
    int n = blockIdx.x * 256 + threadIdx.x;
    if (n >= NN) return;
    float hv[32];
#pragma unroll
    for (int j = 0; j < 32; j++) hv[j] = 0.f;
    int id = ids[n];
    const float4* e4 = (const float4*)(emb + (size_t)id * 16);
#pragma unroll
    for (int k4 = 0; k4 < 4; k4++) {
        float4 xv = e4[k4];
        const float* wr = W + k4 * 4 * 32;
#pragma unroll
        for (int j = 0; j < 32; j++)
            hv[j] += xv.x * wr[j] + xv.y * wr[32 + j] + xv.z * wr[64 + j] + xv.w * wr[96 + j];
    }
    float f = feat[n];
#pragma unroll
    for (int j = 0; j < 32; j++) hv[j] += f * W[16 * 32 + j];
    float s = 0.f, d = 0.f;
#pragma unroll
    for (int j = 0; j < 32; j++) { s += hv[j] * avs[j]; d += hv[j] * avd[j]; }
    as_[n] = s;
    ad_[n] = d;
    float4* h4 = (float4*)(h + (size_t)n * 32);
#pragma unroll
    for (int q = 0; q < 8; q++)
        h4[q] = make_float4(hv[4 * q], hv[4 * q + 1], hv[4 * q + 2], hv[4 * q + 3]);
}

__global__ void k_h2(const float* __restrict__ x, const float* __restrict__ W,
                     const float* __restrict__ avs, const float* __restrict__ avd,
                     float* __restrict__ h, float* __restrict__ as_, float* __restrict__ ad_) {
    int n = blockIdx.x * 256 + threadIdx.x;
    if (n >= NN) return;
    float hv[32];
#pragma unroll
    for (int j = 0; j < 32; j++) hv[j] = 0.f;
    const float4* x4 = (const float4*)(x + (size_t)n * 32);
#pragma unroll
    for (int k4 = 0; k4 < 8; k4++) {
        float4 xv = x4[k4];
        const float* wr = W + k4 * 4 * 32;
#pragma unroll
        for (int j = 0; j < 32; j++)
            hv[j] += xv.x * wr[j] + xv.y * wr[32 + j] + xv.z * wr[64 + j] + xv.w * wr[96 + j];
    }
    float s = 0.f, d = 0.f;
#pragma unroll
    for (int j = 0; j < 32; j++) { s += hv[j] * avs[j]; d += hv[j] * avd[j]; }
    as_[n] = s;
    ad_[n] = d;
    float4* h4 = (float4*)(h + (size_t)n * 32);
#pragma unroll
    for (int q = 0; q < 8; q++)
        h4[q] = make_float4(hv[4 * q], hv[4 * q + 1], hv[4 * q + 2], hv[4 * q + 3]);
}

// ---------------- GAT aggregation: wave per node, two-phase ----------------
// Phase A: lanes = 64 edges -> exp once per edge, {src*32, ex} to LDS.
// Phase B: lanes = 2 slots x 32 comps -> broadcast LDS read + h-row gather + fma.
template <bool FINAL>
__global__ void k_gat(const int* __restrict__ offs, const int2* __restrict__ csr,
                      const float* __restrict__ h, const float* __restrict__ as_,
                      const float* __restrict__ ad_, const float* __restrict__ cbuf,
                      int cidx, const float* __restrict__ bias,
                      const float* __restrict__ lw, const float* __restrict__ lb,
                      float* __restrict__ out) {
    __shared__ int2 xb[4][64];
    int wid = threadIdx.x >> 6;
    int node = blockIdx.x * 4 + wid;
    if (node >= NN) return;
    int lane = threadIdx.x & 63;
    int comp = lane & 31;
    int slot = lane >> 5;
    int base = offs[node];
    int cnt = offs[node + 1] - base;       // >= 1 (self-loop)
    float c = cbuf[cidx];
    float adn = ad_[node];
    float acc0 = 0.f, acc1 = 0.f, exs = 0.f;
    for (int cb = 0; cb < cnt; cb += 64) {
        // ---- phase A: one edge per lane ----
        int idx = cb + lane;
        bool val = idx < cnt;
        int2 e = csr[base + (val ? idx : 0)];
        int s = e.x & 0x1FFFF;
        float a = as_[s] + adn + c * __int_as_float(e.y);
        a = (a >= 0.f) ? a : SLOPE * a;
        float ex = val ? __expf(a) : 0.f;
        exs += ex;
        xb[wid][lane] = make_int2(s << 5, __float_as_int(ex));
        // ---- phase B: 2 slots x 32 comps, 4 edges per iter ----
        int m = min(cnt - cb, 64);
        for (int j = 0; j < m; j += 4) {
            int2 p0 = xb[wid][j + slot];
            int2 p1 = xb[wid][j + 2 + slot];
            acc0 += __int_as_float(p0.y) * h[p0.x + comp];
            acc1 += __int_as_float(p1.y) * h[p1.x + comp];
        }
    }
    float acc = acc0 + acc1;
    acc += __shfl_xor(acc, 32);            // combine the two edge slots
#pragma unroll
    for (int off = 1; off < 64; off <<= 1) exs += __shfl_xor(exs, off);
    float o = acc / (exs + 1e-16f) + bias[comp];
    if (!FINAL) {
        o = fmaxf(o, 0.f);
        if (lane < 32) out[(size_t)node * 32 + comp] = o;
    } else {
        float y = o * lw[comp];            // fused final linear 32 -> 1
#pragma unroll
        for (int off = 16; off >= 1; off >>= 1) y += __shfl_xor(y, off);
        if (lane == 0) out[node] = y + lb[0];
    }
}

// ---------------- launch ----------------

extern "C" void kernel_launch(void* const* d_in, const int* in_sizes, int n_in,
                              void* d_out, int out_size, void* d_ws, size_t ws_size,
                              hipStream_t stream) {
    const int* x_ids = (const int*)d_in[0];
    const float* x_feat = (const float*)d_in[1];
    const int* src = (const int*)d_in[2];
    const int* dst = (const int*)d_in[3];
    const float* eattr = (const float*)d_in[4];
    const float* emb = (const float*)d_in[5];
    const float* W1 = (const float*)d_in[6];
    const float* a_s1 = (const float*)d_in[7];
    const float* a_d1 = (const float*)d_in[8];
    const float* We1 = (const float*)d_in[9];
    const float* a_e1 = (const float*)d_in[10];
    const float* b1 = (const float*)d_in[11];
    const float* W2 = (const float*)d_in[12];
    const float* a_s2 = (const float*)d_in[13];
    const float* a_d2 = (const float*)d_in[14];
    const float* We2 = (const float*)d_in[15];
    const float* a_e2 = (const float*)d_in[16];
    const float* b2 = (const float*)d_in[17];
    const float* lin_w = (const float*)d_in[18];
    const float* lin_b = (const float*)d_in[19];

    char* p = (char*)d_ws;
    auto alloc = [&](size_t bytes) {
        void* r = (void*)p;
        p += (bytes + 255) & ~(size_t)255;
        return r;
    };
    int* cnt = (int*)alloc(NBK * 4);
    int* sbase = (int*)alloc(NBK * 4);
    int* fbase = (int*)alloc(NBK * 4);
    int* curA = (int*)alloc(NBK * 4);
    float* cbuf = (float*)alloc(2 * 4);
    int* offs = (int*)alloc((NN + 1) * 4);
    float* asb = (float*)alloc(NN * 4);
    float* adb = (float*)alloc(NN * 4);
    int2* csr = (int2*)alloc((size_t)EP * 8);
    // stage (EE*8 = 25.6MB) is dead after k_build; alias with hbuf+x2 (2*12.8MB)
    void* regionA = alloc((size_t)EE * 8);
    int2* stage = (int2*)regionA;
    float* hbuf = (float*)regionA;
    float* x2 = hbuf + (size_t)NN * 32;
    (void)ws_size; (void)in_sizes; (void)n_in; (void)out_size;

    hipMemsetAsync(cnt, 0, NBK * 4, stream);

    const int HB = (EE + 4095) / 4096;      // 782
    const int BB = (EE + 8191) / 8192;      // 391
    const int NBT = (NN + 255) / 256;       // 391
    const int NW = (NN + 3) / 4;            // 25000, 4 waves/block

    k_hist<<<HB, 256, 0, stream>>>(dst, cnt);
    k_scanb<<<1, 512, 0, stream>>>(cnt, sbase, fbase, curA);
    k_bucket<<<BB, 256, 0, stream>>>(src, dst, eattr, curA, stage);
    k_build<<<NBK, 256, 0, stream>>>(cnt, sbase, fbase, stage, csr, offs);
    k_const<<<1, 64, 0, stream>>>(We1, a_e1, We2, a_e2, cbuf);

    k_h1<<<NBT, 256, 0, stream>>>(x_ids, x_feat, emb, W1, a_s1, a_d1, hbuf, asb, adb);
    k_gat<false><<<NW, 256, 0, stream>>>(offs, csr, hbuf, asb, adb, cbuf, 0, b1,
                                         nullptr, nullptr, x2);
    k_h2<<<NBT, 256, 0, stream>>>(x2, W2, a_s2, a_d2, hbuf, asb, adb);
    k_gat<true><<<NW, 256, 0, stream>>>(offs, csr, hbuf, asb, adb, cbuf, 1, b2,
                                        lin_w, lin_b, (float*)d_out);
}